// Round 1
// baseline (621.428 us; speedup 1.0000x reference)
//
#include <hip/hip_runtime.h>

#define NV 20000          // vertices
#define NE 4096           // hyperedges
#define FT 128            // features
#define NW_E 128          // u32 words per packed vertex row  (E/32)
#define NW_V 625          // u32 words per packedT edge row   (N/32), 625*32 == 20000 exactly

typedef __attribute__((ext_vector_type(8))) short short8v;   // 8 bf16 (4 VGPRs) — MFMA A/B frag
typedef __attribute__((ext_vector_type(4))) float float4v;   // 4 fp32 — MFMA C/D frag

__device__ __forceinline__ unsigned short f2bf(float f) {    // fp32 -> bf16 RNE
    unsigned u = __float_as_uint(f);
    u += 0x7FFFu + ((u >> 16) & 1u);
    return (unsigned short)(u >> 16);
}
// two H-bits -> packed bf16x2 {0.0 or 1.0, 0.0 or 1.0}
__device__ __forceinline__ unsigned pair_bf(unsigned w, int b) {
    return (((w >> b) & 1u) ? 0x3F80u : 0u) | (((w >> (b + 1)) & 1u) ? 0x3F800000u : 0u);
}
// LDS tile: rows of 64 bf16 (128B), 16B chunks XOR-swizzled by row to kill bank conflicts
__device__ __forceinline__ int lds_off(int r, int chunk) {
    return r * 128 + ((chunk ^ (r & 7)) << 4);
}

// ---------------- 1. pack H rows to bits + vertex degree ----------------
__global__ __launch_bounds__(128) void k_pack(const int* __restrict__ H,
                                              unsigned* __restrict__ packed,
                                              float* __restrict__ dv) {
    int n = blockIdx.x, t = threadIdx.x;
    const uint4* row = reinterpret_cast<const uint4*>(H + (size_t)n * NE + t * 32);
    unsigned m = 0;
#pragma unroll
    for (int i = 0; i < 8; ++i) {
        uint4 v = row[i];
        m |= (v.x ? 1u : 0u) << (i * 4 + 0);
        m |= (v.y ? 1u : 0u) << (i * 4 + 1);
        m |= (v.z ? 1u : 0u) << (i * 4 + 2);
        m |= (v.w ? 1u : 0u) << (i * 4 + 3);
    }
    packed[n * NW_E + t] = m;
    int c = __popc(m);
    __shared__ int red[2];
    for (int o = 32; o > 0; o >>= 1) c += __shfl_down(c, o, 64);
    if ((t & 63) == 0) red[t >> 6] = c;
    __syncthreads();
    if (t == 0) {
        int deg = red[0] + red[1];
        dv[n] = deg > 0 ? 1.0f / sqrtf((float)deg) : 1.0f;
    }
}

// ---------------- 2. bit-transpose packed -> packedT via ballot ----------------
__global__ __launch_bounds__(256) void k_btrans(const unsigned* __restrict__ packed,
                                                unsigned* __restrict__ packedT) {
    int lane = threadIdx.x & 63;
    int w = threadIdx.x >> 6;
    int ew = blockIdx.y * 4 + w;              // which e-word column (0..127)
    int n = blockIdx.x * 64 + lane;           // 64 vertex rows per wave
    unsigned wv = (n < NV) ? packed[n * NW_E + ew] : 0u;
    unsigned my = 0;
#pragma unroll
    for (int j = 0; j < 32; ++j) {
        unsigned long long m = __ballot(((wv >> j) & 1u) != 0);
        unsigned part = (lane < 32) ? (unsigned)m : (unsigned)(m >> 32);
        if ((lane & 31) == j) my = part;
    }
    int nw = blockIdx.x * 2 + (lane >> 5);
    int e = ew * 32 + (lane & 31);
    if (nw < NW_V) packedT[e * NW_V + nw] = my;
}

// ---------------- 3. edge degree = popcount of packedT rows ----------------
__global__ __launch_bounds__(64) void k_edeg(const unsigned* __restrict__ packedT,
                                             float* __restrict__ de) {
    int e = blockIdx.x, l = threadIdx.x;
    const unsigned* row = packedT + e * NW_V;
    int c = 0;
    for (int i = l; i < NW_V; i += 64) c += __popc(row[i]);
    for (int o = 32; o > 0; o >>= 1) c += __shfl_down(c, o, 64);
    if (l == 0) de[e] = c > 0 ? 1.0f / (float)c : 1.0f;
}

// ---------------- 4. Ybf[f][n] = bf16(dv[n] * X[n][f])  (transposed, f-major) ----------------
__global__ __launch_bounds__(256) void k_ybft(const float* __restrict__ X,
                                              const float* __restrict__ dv,
                                              unsigned short* __restrict__ Ybf) {
    int t = threadIdx.x;
    int f = t & 127;
    int nb = (blockIdx.x * 2 + (t >> 7)) * 8;   // 1250 blocks * 2 * 8 == 20000 exactly
    unsigned short h[8];
#pragma unroll
    for (int i = 0; i < 8; ++i) {
        float v = X[(size_t)(nb + i) * FT + f] * dv[nb + i];
        h[i] = f2bf(v);
    }
    uint4 u;
    u.x = (unsigned)h[0] | ((unsigned)h[1] << 16);
    u.y = (unsigned)h[2] | ((unsigned)h[3] << 16);
    u.z = (unsigned)h[4] | ((unsigned)h[5] << 16);
    u.w = (unsigned)h[6] | ((unsigned)h[7] << 16);
    *reinterpret_cast<uint4*>(Ybf + (size_t)f * NV + nb) = u;
}

// ---------------- 5. mm1: Tt[f][e] partials = sum_n Ybf[f][n] * H[n][e], split-K ----------------
__global__ __launch_bounds__(256, 2) void k_mm1(const unsigned short* __restrict__ Ybf,
                                                const unsigned* __restrict__ packedT,
                                                float* __restrict__ P, int chunkK) {
    __shared__ __align__(16) unsigned char sA[128 * 128];   // A: f x k(n), bf16
    __shared__ __align__(16) unsigned char sB[128 * 128];   // B: e x k(n), bf16
    int t = threadIdx.x;
    int et = blockIdx.x & 31, kp = blockIdx.x >> 5;
    int e0 = et * 128;
    int kbeg = kp * chunkK;
    int iters = chunkK >> 6;

    float4v acc[4][4];
#pragma unroll
    for (int i = 0; i < 4; ++i)
#pragma unroll
        for (int j = 0; j < 4; ++j)
#pragma unroll
            for (int r = 0; r < 4; ++r) acc[i][j][r] = 0.0f;

    int fA = t & 127;                 // distinct LDS row per lane -> conflict-free ds_write_b128
    int chbA = (t >> 7) * 4;
    const unsigned short* arow = Ybf + (size_t)fA * NV;
    int eB = t & 127;
    int hB = t >> 7;
    const unsigned* brow = packedT + (size_t)(e0 + eB) * NW_V;

    int wave = t >> 6, lane = t & 63;
    int wm0 = (wave & 1) * 64, wc0 = (wave >> 1) * 64;
    int r0 = lane & 15, q = lane >> 4;

    for (int it = 0; it < iters; ++it) {
        int k0 = kbeg + it * 64;
        // stage A: 128 f-rows x 64 n (bf16), thread reads one full 64B line
#pragma unroll
        for (int c = 0; c < 4; ++c) {
            int ch = chbA + c;
            int n = k0 + ch * 8;
            uint4 v = {0, 0, 0, 0};
            if (n < NV) v = *reinterpret_cast<const uint4*>(arow + n);
            *reinterpret_cast<uint4*>(sA + lds_off(fA, ch)) = v;
        }
        // stage B: unpack 32 H-bits -> 32 bf16
        {
            int nw = (k0 >> 5) + hB;
            unsigned wv = (nw < NW_V) ? brow[nw] : 0u;
#pragma unroll
            for (int c = 0; c < 4; ++c) {
                int b0 = c * 8;
                uint4 u;
                u.x = pair_bf(wv, b0);     u.y = pair_bf(wv, b0 + 2);
                u.z = pair_bf(wv, b0 + 4); u.w = pair_bf(wv, b0 + 6);
                *reinterpret_cast<uint4*>(sB + lds_off(eB, hB * 4 + c)) = u;
            }
        }
        __syncthreads();
#pragma unroll
        for (int ks = 0; ks < 2; ++ks) {
            short8v a[4], b[4];
#pragma unroll
            for (int mi = 0; mi < 4; ++mi)
                a[mi] = *reinterpret_cast<const short8v*>(sA + lds_off(wm0 + mi * 16 + r0, ks * 4 + q));
#pragma unroll
            for (int ci = 0; ci < 4; ++ci)
                b[ci] = *reinterpret_cast<const short8v*>(sB + lds_off(wc0 + ci * 16 + r0, ks * 4 + q));
#pragma unroll
            for (int mi = 0; mi < 4; ++mi)
#pragma unroll
                for (int ci = 0; ci < 4; ++ci)
                    acc[mi][ci] = __builtin_amdgcn_mfma_f32_16x16x32_bf16(a[mi], b[ci], acc[mi][ci], 0, 0, 0);
        }
        __syncthreads();
    }
    float* Pp = P + (size_t)kp * (128 * 4096);
#pragma unroll
    for (int mi = 0; mi < 4; ++mi)
#pragma unroll
        for (int ci = 0; ci < 4; ++ci) {
            int f = wm0 + mi * 16 + q * 4;
            int e = e0 + wc0 + ci * 16 + r0;
#pragma unroll
            for (int r = 0; r < 4; ++r)
                Pp[(size_t)(f + r) * 4096 + e] = acc[mi][ci][r];
        }
}

// ---------------- 6. reduce split-K partials ----------------
__global__ __launch_bounds__(256) void k_reduce(const float4v* __restrict__ P,
                                                float4v* __restrict__ Tt, int S) {
    int i = blockIdx.x * 256 + threadIdx.x;   // 131072 float4 total
    float4v a = P[i];
    for (int p = 1; p < S; ++p) a += P[(size_t)p * 131072 + i];
    Tt[i] = a;
}

// ---------------- 7. Ubf[g][e] = bf16( de[e] * sum_f W[f][g] * Tt[f][e] ) ----------------
__global__ __launch_bounds__(256) void k_ut(const float* __restrict__ Tt,
                                            const float* __restrict__ W,
                                            const float* __restrict__ de,
                                            unsigned short* __restrict__ Ubf) {
    int t = threadIdx.x;
    int e = blockIdx.x * 64 + (t & 63);
    int g0 = blockIdx.y * 16 + (t >> 6) * 4;
    float a0 = 0, a1 = 0, a2 = 0, a3 = 0;
    for (int f = 0; f < 128; ++f) {
        float tv = Tt[(size_t)f * 4096 + e];
        float4 wv = *reinterpret_cast<const float4*>(W + f * 128 + g0);
        a0 += tv * wv.x; a1 += tv * wv.y; a2 += tv * wv.z; a3 += tv * wv.w;
    }
    float d = de[e];
    Ubf[(size_t)(g0 + 0) * 4096 + e] = f2bf(a0 * d);
    Ubf[(size_t)(g0 + 1) * 4096 + e] = f2bf(a1 * d);
    Ubf[(size_t)(g0 + 2) * 4096 + e] = f2bf(a2 * d);
    Ubf[(size_t)(g0 + 3) * 4096 + e] = f2bf(a3 * d);
}

// ---------------- 8. mm2: out[n][g] = dv[n] * sum_e H[n][e]*Ubf[g][e] + bias[g] ----------------
__global__ __launch_bounds__(256, 2) void k_mm2(const unsigned* __restrict__ packed,
                                                const unsigned short* __restrict__ Ubf,
                                                const float* __restrict__ dv,
                                                const float* __restrict__ bias,
                                                float* __restrict__ out) {
    __shared__ __align__(16) unsigned char sA[128 * 128];   // A: n x k(e), bf16
    __shared__ __align__(16) unsigned char sB[64 * 128];    // B: g x k(e), bf16
    int t = threadIdx.x;
    int mt = blockIdx.x >> 1, half = blockIdx.x & 1;
    int n0 = mt * 128, g0 = half * 64;

    float4v acc[4][2];
#pragma unroll
    for (int i = 0; i < 4; ++i)
#pragma unroll
        for (int j = 0; j < 2; ++j)
#pragma unroll
            for (int r = 0; r < 4; ++r) acc[i][j][r] = 0.0f;

    int nA = t & 127, hA = t >> 7;
    int gB = t & 63, chbB = (t >> 6) * 2;
    const unsigned short* brow = Ubf + (size_t)(g0 + gB) * 4096;

    int wave = t >> 6, lane = t & 63;
    int wm0 = (wave & 1) * 64, wc0 = (wave >> 1) * 32;
    int r0 = lane & 15, q = lane >> 4;

    for (int k0 = 0; k0 < 4096; k0 += 64) {
        // stage A from packed bits
        {
            unsigned wv = (n0 + nA < NV) ? packed[(size_t)(n0 + nA) * NW_E + (k0 >> 5) + hA] : 0u;
#pragma unroll
            for (int c = 0; c < 4; ++c) {
                int b0 = c * 8;
                uint4 u;
                u.x = pair_bf(wv, b0);     u.y = pair_bf(wv, b0 + 2);
                u.z = pair_bf(wv, b0 + 4); u.w = pair_bf(wv, b0 + 6);
                *reinterpret_cast<uint4*>(sA + lds_off(nA, hA * 4 + c)) = u;
            }
        }
        // stage B from Ubf (g-major, e-contiguous)
#pragma unroll
        for (int c = 0; c < 2; ++c) {
            int ch = chbB + c;
            uint4 v = *reinterpret_cast<const uint4*>(brow + k0 + ch * 8);
            *reinterpret_cast<uint4*>(sB + lds_off(gB, ch)) = v;
        }
        __syncthreads();
#pragma unroll
        for (int ks = 0; ks < 2; ++ks) {
            short8v a[4], b[2];
#pragma unroll
            for (int mi = 0; mi < 4; ++mi)
                a[mi] = *reinterpret_cast<const short8v*>(sA + lds_off(wm0 + mi * 16 + r0, ks * 4 + q));
#pragma unroll
            for (int ci = 0; ci < 2; ++ci)
                b[ci] = *reinterpret_cast<const short8v*>(sB + lds_off(wc0 + ci * 16 + r0, ks * 4 + q));
#pragma unroll
            for (int mi = 0; mi < 4; ++mi)
#pragma unroll
                for (int ci = 0; ci < 2; ++ci)
                    acc[mi][ci] = __builtin_amdgcn_mfma_f32_16x16x32_bf16(a[mi], b[ci], acc[mi][ci], 0, 0, 0);
        }
        __syncthreads();
    }
#pragma unroll
    for (int ci = 0; ci < 2; ++ci) {
        int g = g0 + wc0 + ci * 16 + r0;
        float bg = bias[g];
#pragma unroll
        for (int mi = 0; mi < 4; ++mi) {
#pragma unroll
            for (int r = 0; r < 4; ++r) {
                int n = n0 + wm0 + mi * 16 + q * 4 + r;
                if (n < NV) out[(size_t)n * 128 + g] = dv[n] * acc[mi][ci][r] + bg;
            }
        }
    }
}

extern "C" void kernel_launch(void* const* d_in, const int* in_sizes, int n_in,
                              void* d_out, int out_size, void* d_ws, size_t ws_size,
                              hipStream_t stream) {
    const float* X    = (const float*)d_in[0];
    const int*   H    = (const int*)d_in[1];
    const float* W    = (const float*)d_in[2];
    const float* bias = (const float*)d_in[3];
    float* out = (float*)d_out;

    char* ws = (char*)d_ws;
    size_t off = 0;
    auto alloc = [&](size_t sz) { char* p = ws + off; off += (sz + 255) & ~(size_t)255; return p; };
    unsigned*       packed  = (unsigned*)alloc((size_t)NV * NW_E * 4);      // 10.24 MB
    unsigned*       packedT = (unsigned*)alloc((size_t)NE * NW_V * 4);      // 10.24 MB
    unsigned short* Ybf     = (unsigned short*)alloc((size_t)FT * NV * 2);  //  5.12 MB
    float*          Tt      = (float*)alloc((size_t)FT * NE * 4);           //  2.10 MB
    unsigned short* Ubf     = (unsigned short*)alloc((size_t)FT * NE * 2);  //  1.05 MB
    float*          dv      = (float*)alloc((size_t)NV * 4);
    float*          de      = (float*)alloc((size_t)NE * 4);
    size_t fixed = off;

    // split-K factor for mm1 sized to available workspace (16 * 2MB partials ideal)
    long long avail = (long long)ws_size - (long long)fixed;
    int S = (int)(avail / (128LL * 4096 * 4));
    if (S > 16) S = 16;
    if (S < 1) S = 1;
    float* P1 = (float*)(ws + fixed);
    int chunkK = ((NV + S * 64 - 1) / (S * 64)) * 64;

    k_pack  <<<NV, 128, 0, stream>>>(H, packed, dv);
    k_btrans<<<dim3(313, 32), 256, 0, stream>>>(packed, packedT);
    k_edeg  <<<NE, 64, 0, stream>>>(packedT, de);
    k_ybft  <<<1250, 256, 0, stream>>>(X, dv, Ybf);
    k_mm1   <<<32 * S, 256, 0, stream>>>(Ybf, packedT, P1, chunkK);
    k_reduce<<<512, 256, 0, stream>>>((const float4v*)P1, (float4v*)Tt, S);
    k_ut    <<<dim3(64, 8), 256, 0, stream>>>(Tt, W, de, Ubf);
    k_mm2   <<<314, 256, 0, stream>>>(packed, Ubf, dv, bias, out);
}